// Round 15
// baseline (112.600 us; speedup 1.0000x reference)
//
#include <hip/hip_runtime.h>
#include <stdint.h>

#define D_MODEL 1024
#define NHEAD 16
#define DK 64
#define BATCH 2
#define SEQ 2048
#define MROWS (BATCH * SEQ) /* 4096 */
#define KVB 128
#define NIT (SEQ / KVB) /* 16 */
// 0.125 * log2(e): folded into Q so QK^T logits are base-2
#define QSCALE 0.18033688011112042f

typedef __attribute__((ext_vector_type(8))) __bf16 bf16x8;
typedef __attribute__((ext_vector_type(2))) __bf16 bf16x2;
typedef __attribute__((ext_vector_type(4))) float f32x4;
typedef __attribute__((ext_vector_type(4))) unsigned int u32x4;
typedef __attribute__((ext_vector_type(2))) unsigned int u32x2;

#if defined(__has_builtin)
#if __has_builtin(__builtin_amdgcn_permlane32_swap) && \
    __has_builtin(__builtin_amdgcn_permlane16_swap)
#define HAVE_PERMLANE_SWAP 1
#endif
#endif
#ifndef HAVE_PERMLANE_SWAP
#define HAVE_PERMLANE_SWAP 0
#endif

__device__ __forceinline__ float exp2_hw(float x) {
  return __builtin_amdgcn_exp2f(x);  // v_exp_f32 (base-2 native)
}

__device__ __forceinline__ f32x4 f4zero() {
  f32x4 z = {0.f, 0.f, 0.f, 0.f};
  return z;
}

__device__ __forceinline__ f32x4 mfma_bf16(bf16x8 a, bf16x8 b, f32x4 c) {
  return __builtin_amdgcn_mfma_f32_16x16x32_bf16(a, b, c, 0, 0, 0);
}

// async global->LDS, 16B per lane; LDS dest = wave-uniform base + lane*16
__device__ __forceinline__ void gload_lds16(const void* g, void* l) {
  __builtin_amdgcn_global_load_lds(
      (const __attribute__((address_space(1))) unsigned int*)g,
      (__attribute__((address_space(3))) unsigned int*)l, 16, 0, 0);
}

__device__ __forceinline__ unsigned short f2b(float x) {  // RNE fp32->bf16
  unsigned int u = __float_as_uint(x);
  u += 0x7fffu + ((u >> 16) & 1u);
  return (unsigned short)(u >> 16);
}

#if HAVE_PERMLANE_SWAP
__device__ __forceinline__ u32x2 pl32(unsigned int a, unsigned int b) {
  return __builtin_amdgcn_permlane32_swap(a, b, false, false);
}
__device__ __forceinline__ u32x2 pl16(unsigned int a, unsigned int b) {
  return __builtin_amdgcn_permlane16_swap(a, b, false, false);
}
#endif

// ------- fp32 -> bf16 convert: WEIGHTS ONLY (activations consumed fp32) -----
__global__ void cvt_w_kernel(const float* __restrict__ wq, const float* __restrict__ wk,
                             const float* __restrict__ wv, const float* __restrict__ wo,
                             unsigned short* __restrict__ wout) {
  const size_t SZW = (size_t)D_MODEL * D_MODEL;
  const int bid = blockIdx.x;
  const int seg = bid >> 10, ib = bid & 1023;
  const float* in = seg == 0 ? wq : seg == 1 ? wk : seg == 2 ? wv : wo;
  unsigned short* out = wout + (size_t)seg * SZW;
  const int i = ib * 256 + threadIdx.x;
  float4 x = ((const float4*)in)[i];
  ushort4 r;
  r.x = f2b(x.x); r.y = f2b(x.y); r.z = f2b(x.z); r.w = f2b(x.w);
  ((ushort4*)out)[i] = r;
}

// -------- GEMM 128x128, SINGLE-BARRIER full double-buffer -------------------
// One fp32 operand (AF32 or BF32) reg-staged (linear lane mapping, conflict-
// free; source-side chunk pre-swizzle); the bf16 operand via gload_lds.
// Per K-step: {FLOAD+gloadB -> nxt} || MFMA(cur) ; FWRITE(nxt) ; ONE barrier.
// Prefetch latency hides under the 16-MFMA block. BROW: bias by output ROW.
template <int AF32, int BF32, int BROW>
__device__ __forceinline__ void gemm_body128(const void* __restrict__ Aptr,
                                             const void* __restrict__ Bptr,
                                             const float* __restrict__ bias,
                                             float scale,
                                             unsigned short* __restrict__ outb,
                                             int bm, int bn, int M, int N, int K,
                                             unsigned short* sA0, unsigned short* sA1,
                                             unsigned short* sB0, unsigned short* sB1) {
  const int tid = threadIdx.x;
  const int w = tid >> 6, l = tid & 63;
  const int rowBase = bm << 7, colBase = bn << 7;
  const int wm = w >> 1, wn = w & 1;
  const int g = l >> 4, c16 = l & 15;

  unsigned short* sAb[2] = {sA0, sA1};
  unsigned short* sBb[2] = {sB0, sB1};

  f32x4 acc[4][4];
#pragma unroll
  for (int i = 0; i < 4; i++)
#pragma unroll
    for (int j = 0; j < 4; j++) acc[i][j] = f4zero();

  const int rloc = l >> 2;               // 16 rows per wave-pass (64B rows)
  const int uch = (l & 3) ^ (rloc & 3);  // pre-swizzled source chunk
  const int lchunk = l & 3;              // physical LDS chunk (linear dest)

  float4 fr[2][2];  // fp32 staging registers
  const float* Ff = AF32 ? (const float*)Aptr : (const float*)Bptr;
  const int fBase = AF32 ? rowBase : colBase;

  auto FLOAD = [&](int kk) {
#pragma unroll
    for (int p = 0; p < 2; p++) {
      const size_t base =
          (size_t)(fBase + w * 16 + p * 64 + rloc) * K + kk + uch * 8;
      fr[p][0] = *(const float4*)&Ff[base];
      fr[p][1] = *(const float4*)&Ff[base + 4];
    }
  };
  auto FWRITE = [&](unsigned short* sDst) {
#pragma unroll
    for (int p = 0; p < 2; p++) {
      bf16x8 rr;
      rr[0] = (__bf16)fr[p][0].x; rr[1] = (__bf16)fr[p][0].y;
      rr[2] = (__bf16)fr[p][0].z; rr[3] = (__bf16)fr[p][0].w;
      rr[4] = (__bf16)fr[p][1].x; rr[5] = (__bf16)fr[p][1].y;
      rr[6] = (__bf16)fr[p][1].z; rr[7] = (__bf16)fr[p][1].w;
      // linear: byte (w*16+p*64+rloc)*64 + (l&3)*16 == r0*64 + l*16
      *(bf16x8*)&sDst[(w * 16 + p * 64 + rloc) * 32 + lchunk * 8] = rr;
    }
  };
  auto GLOADS = [&](int kk, unsigned short* sDstA, unsigned short* sDstB) {
#pragma unroll
    for (int h = 0; h < 2; h++) {
      const int r0 = w * 16 + h * 64;
      if (!AF32)
        gload_lds16((const unsigned short*)Aptr +
                        (size_t)(rowBase + r0 + rloc) * K + kk + uch * 8,
                    &sDstA[r0 * 32]);
      if (!BF32)
        gload_lds16((const unsigned short*)Bptr +
                        (size_t)(colBase + r0 + rloc) * K + kk + uch * 8,
                    &sDstB[r0 * 32]);
    }
  };
  auto COMPUTE = [&](const unsigned short* sAr, const unsigned short* sBr) {
    bf16x8 af[4], bfr[4];
#pragma unroll
    for (int mt = 0; mt < 4; mt++) {
      const int r = wm * 64 + mt * 16 + c16;
      af[mt] = *(const bf16x8*)&sAr[r * 32 + (g ^ (r & 3)) * 8];
    }
#pragma unroll
    for (int nt = 0; nt < 4; nt++) {
      const int r = wn * 64 + nt * 16 + c16;
      bfr[nt] = *(const bf16x8*)&sBr[r * 32 + (g ^ (r & 3)) * 8];
    }
#pragma unroll
    for (int mt = 0; mt < 4; mt++)
#pragma unroll
      for (int nt = 0; nt < 4; nt++)
        acc[mt][nt] = mfma_bf16(af[mt], bfr[nt], acc[mt][nt]);
  };

  // prologue: fill buffer 0
  if (AF32 || BF32) FLOAD(0);
  GLOADS(0, sAb[0], sBb[0]);
  if (AF32) FWRITE(sAb[0]);
  else if (BF32) FWRITE(sBb[0]);
  __syncthreads();  // buf0 ready (vmcnt+lgkm drained)

  auto STEP = [&](int kk, int cur) {  // literal cur only
    const int nxt = cur ^ 1;
    const bool more = kk + 32 < K;
    if (more) {
      if (AF32 || BF32) FLOAD(kk + 32);
      GLOADS(kk + 32, sAb[nxt], sBb[nxt]);
    }
    COMPUTE(sAb[cur], sBb[cur]);  // hides prefetch latency
    if (more) {
      if (AF32) FWRITE(sAb[nxt]);      // nxt last read before prev barrier
      else if (BF32) FWRITE(sBb[nxt]);
    }
    __syncthreads();  // drains prefetch + FWRITE; nxt ready for next STEP
  };
  for (int kk = 0; kk < K; kk += 64) {
    STEP(kk, 0);
    STEP(kk + 32, 1);
  }

  // epilogue: C/D layout row = g*4+i, col = c16
#pragma unroll
  for (int mt = 0; mt < 4; mt++) {
    float brow[4];
    if (BROW) {
#pragma unroll
      for (int i = 0; i < 4; i++)
        brow[i] = bias[rowBase + wm * 64 + mt * 16 + g * 4 + i];
    }
#pragma unroll
    for (int nt = 0; nt < 4; nt++) {
      const int col = colBase + wn * 64 + nt * 16 + c16;
      const float bcol = BROW ? 0.f : bias[col];
#pragma unroll
      for (int i = 0; i < 4; i++) {
        const int row = rowBase + wm * 64 + mt * 16 + g * 4 + i;
        const float bv = BROW ? brow[i] : bcol;
        outb[(size_t)row * N + col] = f2b((acc[mt][nt][i] + bv) * scale);
      }
    }
  }
}

// -------- GEMM 128x64 (two-barrier; output projection, fp32 out) -----------
__device__ __forceinline__ void gemm_body64(const unsigned short* __restrict__ A,
                                            const unsigned short* __restrict__ B,
                                            const float* __restrict__ bias,
                                            float* __restrict__ outf, int bx,
                                            int M, int N, int K,
                                            unsigned short* sA, unsigned short* sB) {
  const int tid = threadIdx.x;
  const int w = tid >> 6, l = tid & 63;
  const int nTN = N >> 6;
  const int bm = bx / nTN, bn = bx % nTN;
  const int rowBase = bm << 7, colBase = bn << 6;
  const int g = l >> 4, c16 = l & 15;

  f32x4 acc[2][4];
#pragma unroll
  for (int i = 0; i < 2; i++)
#pragma unroll
    for (int j = 0; j < 4; j++) acc[i][j] = f4zero();

  const int rloc = l >> 2;
  const int uch = (l & 3) ^ (rloc & 3);

  for (int kk = 0; kk < K; kk += 32) {
    __syncthreads();
    gload_lds16(A + (size_t)(rowBase + w * 16 + rloc) * K + kk + uch * 8,
                &sA[(w * 16) * 32]);
    gload_lds16(A + (size_t)(rowBase + 64 + w * 16 + rloc) * K + kk + uch * 8,
                &sA[(64 + w * 16) * 32]);
    gload_lds16(B + (size_t)(colBase + w * 16 + rloc) * K + kk + uch * 8,
                &sB[(w * 16) * 32]);
    __syncthreads();

    bf16x8 af[2], bfr[4];
#pragma unroll
    for (int mt = 0; mt < 2; mt++) {
      const int r = w * 32 + mt * 16 + c16;
      af[mt] = *(const bf16x8*)&sA[r * 32 + (g ^ (r & 3)) * 8];
    }
#pragma unroll
    for (int nt = 0; nt < 4; nt++) {
      const int r = nt * 16 + c16;
      bfr[nt] = *(const bf16x8*)&sB[r * 32 + (g ^ (r & 3)) * 8];
    }
#pragma unroll
    for (int mt = 0; mt < 2; mt++)
#pragma unroll
      for (int nt = 0; nt < 4; nt++)
        acc[mt][nt] = mfma_bf16(af[mt], bfr[nt], acc[mt][nt]);
  }

#pragma unroll
  for (int mt = 0; mt < 2; mt++)
#pragma unroll
    for (int nt = 0; nt < 4; nt++) {
      const int col = colBase + nt * 16 + c16;
      const float bv = bias[col];
#pragma unroll
      for (int i = 0; i < 4; i++) {
        const int row = rowBase + w * 32 + mt * 16 + g * 4 + i;
        outf[(size_t)row * N + col] = acc[mt][nt][i] + bv;
      }
    }
}

// Q/K projections + TRANSPOSED V projection, one dispatch (3 x 256 blocks).
// Activations consumed DIRECTLY as fp32 (single-barrier dbuf staging).
// XCD-chunked (bm,bn) swizzle for activation-panel L2 locality.
__global__ __launch_bounds__(256, 4) void gemm_qkv_kernel(
    const float* __restrict__ qin, const float* __restrict__ kin,
    const float* __restrict__ vin, const unsigned short* __restrict__ Wbase,
    const float* __restrict__ bq, const float* __restrict__ bk,
    const float* __restrict__ bv, unsigned short* __restrict__ QKout,
    unsigned short* __restrict__ VTout) {
  __shared__ __attribute__((aligned(16))) unsigned short sA[2][128 * 32];
  __shared__ __attribute__((aligned(16))) unsigned short sB[2][128 * 32];
  const int gid = blockIdx.x >> 8, rb = blockIdx.x & 255;
  const int c = rb & 7, j = rb >> 3;  // c = XCD (blockIdx round-robin, 256%8==0)
  const size_t SZA = (size_t)MROWS * D_MODEL;
  const size_t SZW = (size_t)D_MODEL * D_MODEL;
  if (gid < 2) {
    // act[MROWS,K] fp32 @ A; W[N,K] bf16 @ B. bm grouped per XCD.
    const int bm = c * 4 + (j >> 3), bn = j & 7;
    const float* act = gid == 0 ? qin : kin;
    const float* bias = gid == 0 ? bq : bk;
    const float scale = gid == 0 ? QSCALE : 1.0f;
    gemm_body128<1, 0, 0>(act, Wbase + (size_t)gid * SZW, bias, scale,
                          QKout + (size_t)gid * SZA, bm, bn, MROWS, D_MODEL,
                          D_MODEL, sA[0], sA[1], sB[0], sB[1]);
  } else {
    // V^T: W_v[1024,K] bf16 @ A; v-act[MROWS,K] fp32 @ B. bn grouped per XCD.
    const int bm = j & 7, bn = c * 4 + (j >> 3);
    gemm_body128<0, 1, 1>(Wbase + 2 * SZW, vin, bv, 1.0f, VTout, bm, bn,
                          D_MODEL, MROWS, D_MODEL, sA[0], sA[1], sB[0], sB[1]);
  }
}

__global__ __launch_bounds__(256, 4) void gemm_out_kernel(
    const unsigned short* __restrict__ A, const unsigned short* __restrict__ B,
    const float* __restrict__ bias, float* __restrict__ out) {
  __shared__ __attribute__((aligned(16))) unsigned short sA[128 * 32];
  __shared__ __attribute__((aligned(16))) unsigned short sB[64 * 32];
  gemm_body64(A, B, bias, out, blockIdx.x, MROWS, D_MODEL, D_MODEL, sA, sB);
}

// ---------------- flash attention (r10-proven single-pass) ----------------
// 1-D grid 512, XCD-swizzled (K/V L2-local per (b,h)). 4 waves x 32 q-rows.
// KVB=128 double-buffered as TWO 64-key sub-buffers (half the barriers).
// s_setprio(1) around PV MFMA clusters. Scale-free softmax (no max tracking);
// l via ones-MFMA row-sum (row layout, shfl-free finalize).
__global__ __launch_bounds__(256, 2) void attn_kernel(
    const unsigned short* __restrict__ Qh, const unsigned short* __restrict__ Kh,
    const unsigned short* __restrict__ Vt, unsigned short* __restrict__ Xh) {
  __shared__ __attribute__((aligned(16))) unsigned short sK[2][2][64 * 64];
  __shared__ __attribute__((aligned(16))) unsigned short sV[2][2][64 * 64];

  const int tid = threadIdx.x, w = tid >> 6, l = tid & 63;
  const int fid = blockIdx.x;
  const int L = (fid & 7) * 64 + (fid >> 3);  // XCD-chunked bijection (512%8==0)
  const int bh = L >> 4, qx = L & 15;
  const int b = bh >> 4, h = bh & 15;
  const int q0 = qx * 128 + w * 32;
  const int g = l >> 4, c16 = l & 15;

  bf16x8 qf[2][2];
#pragma unroll
  for (int qs = 0; qs < 2; ++qs)
#pragma unroll
    for (int f = 0; f < 2; ++f)
      qf[qs][f] = *(const bf16x8*)&Qh[(size_t)(b * SEQ + q0 + qs * 16 + c16) * D_MODEL +
                                      h * DK + f * 32 + g * 8];

  const u32x4 onesu = {0x3F803F80u, 0x3F803F80u, 0x3F803F80u, 0x3F803F80u};
  const bf16x8 onesf = __builtin_bit_cast(bf16x8, onesu);

  f32x4 acc[2][4], accl[2];
#pragma unroll
  for (int qs = 0; qs < 2; ++qs) {
#pragma unroll
    for (int dt = 0; dt < 4; ++dt) acc[qs][dt] = f4zero();
    accl[qs] = f4zero();
  }

  const int srow = l >> 3, sch = (l & 7) ^ (srow & 7);  // 8 rows/gload (128B rows)

  auto STAGE = [&](int pbuf, int kv0) {
#pragma unroll
    for (int half = 0; half < 2; ++half)
#pragma unroll
      for (int hh = 0; hh < 2; ++hh) {
        const int r0 = w * 16 + hh * 8;
        const int kvh = kv0 + half * 64;
        gload_lds16(
            Kh + (size_t)(b * SEQ + kvh + r0 + srow) * D_MODEL + h * DK + sch * 8,
            &sK[pbuf][half][r0 * 64]);
        gload_lds16(
            Vt + (size_t)(h * DK + r0 + srow) * MROWS + b * SEQ + kvh + sch * 8,
            &sV[pbuf][half][r0 * 64]);
      }
  };

  auto STEPH = [&](const unsigned short* sKp, const unsigned short* sVp) {
    f32x4 st[2][4];
#pragma unroll
    for (int kt = 0; kt < 4; ++kt) {
      bf16x8 kf[2];
#pragma unroll
      for (int f = 0; f < 2; ++f) {
        const int key = kt * 16 + c16;
        const int ch = (f * 4 + g) ^ (key & 7);
        kf[f] = *(const bf16x8*)&sKp[key * 64 + ch * 8];
      }
#pragma unroll
      for (int qs = 0; qs < 2; ++qs) {
        f32x4 s = mfma_bf16(kf[0], qf[qs][0], f4zero());
        st[qs][kt] = mfma_bf16(kf[1], qf[qs][1], s);
      }
    }

    unsigned int Qpk[2][4][2];
#pragma unroll
    for (int qs = 0; qs < 2; ++qs)
#pragma unroll
      for (int kt = 0; kt < 4; ++kt) {
        float pv[4];
#pragma unroll
        for (int i = 0; i < 4; ++i) pv[i] = exp2_hw(st[qs][kt][i]);
#pragma unroll
        for (int hh = 0; hh < 2; ++hh) {
          bf16x2 t2;
          t2.x = (__bf16)pv[hh * 2];
          t2.y = (__bf16)pv[hh * 2 + 1];
          Qpk[qs][kt][hh] = __builtin_bit_cast(unsigned int, t2);
        }
      }

#pragma unroll
    for (int ks = 0; ks < 2; ++ks) {
      bf16x8 pfrag[2];
#pragma unroll
      for (int qs = 0; qs < 2; ++qs) {
        unsigned int pw[4];
#if HAVE_PERMLANE_SWAP
#pragma unroll
        for (int hh = 0; hh < 2; ++hh) {
          u32x2 s1 = pl32(Qpk[qs][2 * ks][hh], Qpk[qs][2 * ks + 1][hh]);
          u32x2 s2 = pl16(s1.x, s1.y);
          pw[hh] = s2.x;
          pw[2 + hh] = s2.y;
        }
#else
#pragma unroll
        for (int hh = 0; hh < 2; ++hh) {
          const unsigned int a = Qpk[qs][2 * ks][hh], bb = Qpk[qs][2 * ks + 1][hh];
          const unsigned int as = __shfl_xor((int)a, 32);
          const unsigned int bs = __shfl_xor((int)bb, 32);
          const unsigned int r0 = (l >= 32) ? bs : a;
          const unsigned int r1 = (l >= 32) ? bb : as;
          const unsigned int t0 = __shfl_xor((int)r0, 16);
          const unsigned int t1 = __shfl_xor((int)r1, 16);
          pw[hh] = (g & 1) ? t1 : r0;
          pw[2 + hh] = (g & 1) ? r1 : t0;
        }
#endif
        u32x4 pv4 = {pw[0], pw[1], pw[2], pw[3]};
        pfrag[qs] = __builtin_bit_cast(bf16x8, pv4);
      }
      __builtin_amdgcn_s_setprio(1);
      accl[0] = mfma_bf16(pfrag[0], onesf, accl[0]);
      accl[1] = mfma_bf16(pfrag[1], onesf, accl[1]);
#pragma unroll
      for (int dt = 0; dt < 4; ++dt) {
        const int d = dt * 16 + c16;
        const int ch = (ks * 4 + g) ^ (d & 7);
        bf16x8 vfrag = *(const bf16x8*)&sVp[d * 64 + ch * 8];
        acc[0][dt] = mfma_bf16(pfrag[0], vfrag, acc[0][dt]);
        acc[1][dt] = mfma_bf16(pfrag[1], vfrag, acc[1][dt]);
      }
      __builtin_amdgcn_s_setprio(0);
    }
  };

  STAGE(0, 0);
  __syncthreads();

  for (int it = 0; it < NIT; it += 2) {  // NIT=16 even; literal buffer indices
    if (it + 1 < NIT) STAGE(1, (it + 1) * KVB);
    STEPH(&sK[0][0][0], &sV[0][0][0]);
    STEPH(&sK[0][1][0], &sV[0][1][0]);
    __syncthreads();
    if (it + 2 < NIT) STAGE(0, (it + 2) * KVB);
    STEPH(&sK[1][0][0], &sV[1][0][0]);
    STEPH(&sK[1][1][0], &sV[1][1][0]);
    __syncthreads();
  }

  // finalize: O = acc / l ; accl in ROW layout (no shfl)
#pragma unroll
  for (int qs = 0; qs < 2; ++qs) {
    float linv[4];
#pragma unroll
    for (int i = 0; i < 4; ++i) linv[i] = __builtin_amdgcn_rcpf(accl[qs][i]);
#pragma unroll
    for (int dt = 0; dt < 4; ++dt)
#pragma unroll
      for (int i = 0; i < 4; ++i) {
        const int row = b * SEQ + q0 + qs * 16 + g * 4 + i;
        const int col = h * DK + dt * 16 + c16;
        Xh[(size_t)row * D_MODEL + col] = f2b(acc[qs][dt][i] * linv[i]);
      }
  }
}

// ---------------- host ----------------
extern "C" void kernel_launch(void* const* d_in, const int* in_sizes, int n_in,
                              void* d_out, int out_size, void* d_ws, size_t ws_size,
                              hipStream_t stream) {
  (void)in_sizes; (void)n_in; (void)out_size; (void)ws_size;
  const float* q = (const float*)d_in[0];
  const float* k = (const float*)d_in[1];
  const float* v = (const float*)d_in[2];
  const float* w_q = (const float*)d_in[3];
  const float* b_q = (const float*)d_in[4];
  const float* w_k = (const float*)d_in[5];
  const float* b_k = (const float*)d_in[6];
  const float* w_v = (const float*)d_in[7];
  const float* b_v = (const float*)d_in[8];
  const float* w_o = (const float*)d_in[9];
  const float* b_o = (const float*)d_in[10];

  const size_t SZ_ACT = (size_t)MROWS * D_MODEL;  // elements (4M)
  const size_t SZ_W = (size_t)D_MODEL * D_MODEL;  // elements (1M)
  char* ws = (char*)d_ws;
  // byte layout:
  // [0,8MB):   Xh (attention output, bf16)
  // [24,40MB): Q,K projections (contig)
  // [40,48MB): V^T projection (1024 x 4096)
  // [48,56MB): wq,wk,wv,wo bf16 (contig)
  unsigned short* Xh = (unsigned short*)(ws);
  unsigned short* Qproj = (unsigned short*)(ws + 6 * SZ_ACT);
  unsigned short* Vt = (unsigned short*)(ws + 10 * SZ_ACT);
  unsigned short* wqb = (unsigned short*)(ws + 12 * SZ_ACT);
  unsigned short* wob = (unsigned short*)(ws + 12 * SZ_ACT + 6 * SZ_W);

  cvt_w_kernel<<<4096, 256, 0, stream>>>(w_q, w_k, w_v, w_o, wqb);

  gemm_qkv_kernel<<<3 * 256, 256, 0, stream>>>(q, k, v, wqb, b_q, b_k, b_v,
                                               Qproj, Vt);

  // Q at Qproj, K at Qproj + SZ_ACT (elements), V^T at Vt
  attn_kernel<<<512, 256, 0, stream>>>(Qproj, Qproj + SZ_ACT, Vt, Xh);

  gemm_out_kernel<<<512, 256, 0, stream>>>(Xh, wob, b_o, (float*)d_out);
}

// Round 16
// 109.681 us; speedup vs baseline: 1.0266x; 1.0266x over previous
//
#include <hip/hip_runtime.h>
#include <stdint.h>

#define D_MODEL 1024
#define NHEAD 16
#define DK 64
#define BATCH 2
#define SEQ 2048
#define MROWS (BATCH * SEQ) /* 4096 */
#define KVB 128
#define NIT (SEQ / KVB) /* 16 */
// 0.125 * log2(e): folded into Q so QK^T logits are base-2
#define QSCALE 0.18033688011112042f

typedef __attribute__((ext_vector_type(8))) __bf16 bf16x8;
typedef __attribute__((ext_vector_type(2))) __bf16 bf16x2;
typedef __attribute__((ext_vector_type(4))) float f32x4;
typedef __attribute__((ext_vector_type(4))) unsigned int u32x4;
typedef __attribute__((ext_vector_type(2))) unsigned int u32x2;

#if defined(__has_builtin)
#if __has_builtin(__builtin_amdgcn_permlane32_swap) && \
    __has_builtin(__builtin_amdgcn_permlane16_swap)
#define HAVE_PERMLANE_SWAP 1
#endif
#endif
#ifndef HAVE_PERMLANE_SWAP
#define HAVE_PERMLANE_SWAP 0
#endif

__device__ __forceinline__ float exp2_hw(float x) {
  return __builtin_amdgcn_exp2f(x);  // v_exp_f32 (base-2 native)
}

__device__ __forceinline__ f32x4 f4zero() {
  f32x4 z = {0.f, 0.f, 0.f, 0.f};
  return z;
}

__device__ __forceinline__ f32x4 mfma_bf16(bf16x8 a, bf16x8 b, f32x4 c) {
  return __builtin_amdgcn_mfma_f32_16x16x32_bf16(a, b, c, 0, 0, 0);
}

// async global->LDS, 16B per lane; LDS dest = wave-uniform base + lane*16
__device__ __forceinline__ void gload_lds16(const void* g, void* l) {
  __builtin_amdgcn_global_load_lds(
      (const __attribute__((address_space(1))) unsigned int*)g,
      (__attribute__((address_space(3))) unsigned int*)l, 16, 0, 0);
}

__device__ __forceinline__ unsigned short f2b(float x) {  // RNE fp32->bf16
  unsigned int u = __float_as_uint(x);
  u += 0x7fffu + ((u >> 16) & 1u);
  return (unsigned short)(u >> 16);
}

#if HAVE_PERMLANE_SWAP
__device__ __forceinline__ u32x2 pl32(unsigned int a, unsigned int b) {
  return __builtin_amdgcn_permlane32_swap(a, b, false, false);
}
__device__ __forceinline__ u32x2 pl16(unsigned int a, unsigned int b) {
  return __builtin_amdgcn_permlane16_swap(a, b, false, false);
}
#endif

// ------- fp32 -> bf16 convert: WEIGHTS ONLY (activations consumed fp32) -----
__global__ void cvt_w_kernel(const float* __restrict__ wq, const float* __restrict__ wk,
                             const float* __restrict__ wv, const float* __restrict__ wo,
                             unsigned short* __restrict__ wout) {
  const size_t SZW = (size_t)D_MODEL * D_MODEL;
  const int bid = blockIdx.x;
  const int seg = bid >> 10, ib = bid & 1023;
  const float* in = seg == 0 ? wq : seg == 1 ? wk : seg == 2 ? wv : wo;
  unsigned short* out = wout + (size_t)seg * SZW;
  const int i = ib * 256 + threadIdx.x;
  float4 x = ((const float4*)in)[i];
  ushort4 r;
  r.x = f2b(x.x); r.y = f2b(x.y); r.z = f2b(x.z); r.w = f2b(x.w);
  ((ushort4*)out)[i] = r;
}

// -------- GEMM 128x128 (two-barrier), fp32-or-bf16 operands -----------------
// AF32/BF32: that operand is fp32 in HBM. Reg-staged with the LINEAR lane
// mapping (lane l -> LDS byte r0*64 + l*16, conflict-free like gload_lds) and
// source-side chunk pre-swizzle; loads for tile kk+32 issued after barrier2 so
// HBM latency hides under the 16-MFMA compute (T14). RNE casts == f2b bits.
// BROW: bias indexed by output ROW (transposed V projection).
template <int AF32, int BF32, int BROW>
__device__ __forceinline__ void gemm_body128(const void* __restrict__ Aptr,
                                             const void* __restrict__ Bptr,
                                             const float* __restrict__ bias,
                                             float scale,
                                             unsigned short* __restrict__ outb,
                                             int bm, int bn, int M, int N, int K,
                                             unsigned short* sA, unsigned short* sB) {
  const int tid = threadIdx.x;
  const int w = tid >> 6, l = tid & 63;
  const int rowBase = bm << 7, colBase = bn << 7;
  const int wm = w >> 1, wn = w & 1;
  const int g = l >> 4, c16 = l & 15;

  f32x4 acc[4][4];
#pragma unroll
  for (int i = 0; i < 4; i++)
#pragma unroll
    for (int j = 0; j < 4; j++) acc[i][j] = f4zero();

  const int rloc = l >> 2;               // 16 rows per wave-pass (64B rows)
  const int uch = (l & 3) ^ (rloc & 3);  // pre-swizzled source chunk
  const int lchunk = l & 3;              // physical LDS chunk (linear dest)

  // fp32 reg-staging state (AF32 and BF32 are mutually exclusive here)
  float4 fr[2][2];
  const float* Ff = AF32 ? (const float*)Aptr : (const float*)Bptr;
  const int fBase = AF32 ? rowBase : colBase;

  auto FLOAD = [&](int kk) {
#pragma unroll
    for (int p = 0; p < 2; p++) {
      const size_t base =
          (size_t)(fBase + w * 16 + p * 64 + rloc) * K + kk + uch * 8;
      fr[p][0] = *(const float4*)&Ff[base];
      fr[p][1] = *(const float4*)&Ff[base + 4];
    }
  };
  auto FWRITE = [&](unsigned short* sDst) {
#pragma unroll
    for (int p = 0; p < 2; p++) {
      bf16x8 rr;
      rr[0] = (__bf16)fr[p][0].x; rr[1] = (__bf16)fr[p][0].y;
      rr[2] = (__bf16)fr[p][0].z; rr[3] = (__bf16)fr[p][0].w;
      rr[4] = (__bf16)fr[p][1].x; rr[5] = (__bf16)fr[p][1].y;
      rr[6] = (__bf16)fr[p][1].z; rr[7] = (__bf16)fr[p][1].w;
      // linear: (w*16+p*64+rloc)*64B + (l&3)*16B == r0*64 + l*16
      *(bf16x8*)&sDst[(w * 16 + p * 64 + rloc) * 32 + lchunk * 8] = rr;
    }
  };

  if (AF32 || BF32) FLOAD(0);

  for (int kk = 0; kk < K; kk += 32) {
    __syncthreads();
    if (AF32) {
      FWRITE(sA);
#pragma unroll
      for (int h = 0; h < 2; h++) {
        const int r0 = w * 16 + h * 64;
        gload_lds16((const unsigned short*)Bptr +
                        (size_t)(colBase + r0 + rloc) * K + kk + uch * 8,
                    &sB[r0 * 32]);
      }
    } else if (BF32) {
#pragma unroll
      for (int h = 0; h < 2; h++) {
        const int r0 = w * 16 + h * 64;
        gload_lds16((const unsigned short*)Aptr +
                        (size_t)(rowBase + r0 + rloc) * K + kk + uch * 8,
                    &sA[r0 * 32]);
      }
      FWRITE(sB);
    } else {
#pragma unroll
      for (int h = 0; h < 2; h++) {
        const int r0 = w * 16 + h * 64;
        gload_lds16((const unsigned short*)Aptr +
                        (size_t)(rowBase + r0 + rloc) * K + kk + uch * 8,
                    &sA[r0 * 32]);
        gload_lds16((const unsigned short*)Bptr +
                        (size_t)(colBase + r0 + rloc) * K + kk + uch * 8,
                    &sB[r0 * 32]);
      }
    }
    __syncthreads();
    if ((AF32 || BF32) && kk + 32 < K) FLOAD(kk + 32);  // hide under MFMA

    bf16x8 af[4], bfr[4];
#pragma unroll
    for (int mt = 0; mt < 4; mt++) {
      const int r = wm * 64 + mt * 16 + c16;
      af[mt] = *(const bf16x8*)&sA[r * 32 + (g ^ (r & 3)) * 8];
    }
#pragma unroll
    for (int nt = 0; nt < 4; nt++) {
      const int r = wn * 64 + nt * 16 + c16;
      bfr[nt] = *(const bf16x8*)&sB[r * 32 + (g ^ (r & 3)) * 8];
    }
#pragma unroll
    for (int mt = 0; mt < 4; mt++)
#pragma unroll
      for (int nt = 0; nt < 4; nt++)
        acc[mt][nt] = mfma_bf16(af[mt], bfr[nt], acc[mt][nt]);
  }

  // epilogue: C/D layout row = g*4+i, col = c16
#pragma unroll
  for (int mt = 0; mt < 4; mt++) {
    float brow[4];
    if (BROW) {
#pragma unroll
      for (int i = 0; i < 4; i++)
        brow[i] = bias[rowBase + wm * 64 + mt * 16 + g * 4 + i];
    }
#pragma unroll
    for (int nt = 0; nt < 4; nt++) {
      const int col = colBase + wn * 64 + nt * 16 + c16;
      const float bcol = BROW ? 0.f : bias[col];
#pragma unroll
      for (int i = 0; i < 4; i++) {
        const int row = rowBase + wm * 64 + mt * 16 + g * 4 + i;
        const float bv = BROW ? brow[i] : bcol;
        outb[(size_t)row * N + col] = f2b((acc[mt][nt][i] + bv) * scale);
      }
    }
  }
}

// -------- GEMM 128x64 (two-barrier; output projection, fp32 out) -----------
__device__ __forceinline__ void gemm_body64(const unsigned short* __restrict__ A,
                                            const unsigned short* __restrict__ B,
                                            const float* __restrict__ bias,
                                            float* __restrict__ outf, int bx,
                                            int M, int N, int K,
                                            unsigned short* sA, unsigned short* sB) {
  const int tid = threadIdx.x;
  const int w = tid >> 6, l = tid & 63;
  const int nTN = N >> 6;
  const int bm = bx / nTN, bn = bx % nTN;
  const int rowBase = bm << 7, colBase = bn << 6;
  const int g = l >> 4, c16 = l & 15;

  f32x4 acc[2][4];
#pragma unroll
  for (int i = 0; i < 2; i++)
#pragma unroll
    for (int j = 0; j < 4; j++) acc[i][j] = f4zero();

  const int rloc = l >> 2;
  const int uch = (l & 3) ^ (rloc & 3);

  for (int kk = 0; kk < K; kk += 32) {
    __syncthreads();
    gload_lds16(A + (size_t)(rowBase + w * 16 + rloc) * K + kk + uch * 8,
                &sA[(w * 16) * 32]);
    gload_lds16(A + (size_t)(rowBase + 64 + w * 16 + rloc) * K + kk + uch * 8,
                &sA[(64 + w * 16) * 32]);
    gload_lds16(B + (size_t)(colBase + w * 16 + rloc) * K + kk + uch * 8,
                &sB[(w * 16) * 32]);
    __syncthreads();

    bf16x8 af[2], bfr[4];
#pragma unroll
    for (int mt = 0; mt < 2; mt++) {
      const int r = w * 32 + mt * 16 + c16;
      af[mt] = *(const bf16x8*)&sA[r * 32 + (g ^ (r & 3)) * 8];
    }
#pragma unroll
    for (int nt = 0; nt < 4; nt++) {
      const int r = nt * 16 + c16;
      bfr[nt] = *(const bf16x8*)&sB[r * 32 + (g ^ (r & 3)) * 8];
    }
#pragma unroll
    for (int mt = 0; mt < 2; mt++)
#pragma unroll
      for (int nt = 0; nt < 4; nt++)
        acc[mt][nt] = mfma_bf16(af[mt], bfr[nt], acc[mt][nt]);
  }

#pragma unroll
  for (int mt = 0; mt < 2; mt++)
#pragma unroll
    for (int nt = 0; nt < 4; nt++) {
      const int col = colBase + nt * 16 + c16;
      const float bv = bias[col];
#pragma unroll
      for (int i = 0; i < 4; i++) {
        const int row = rowBase + w * 32 + mt * 16 + g * 4 + i;
        outf[(size_t)row * N + col] = acc[mt][nt][i] + bv;
      }
    }
}

// Q/K projections + TRANSPOSED V projection, one dispatch (3 x 256 blocks).
// Activations consumed DIRECTLY as fp32 (conflict-free reg-staging + T14
// prefetch). XCD-chunked (bm,bn) swizzle for activation-panel L2 locality.
__global__ __launch_bounds__(256, 3) void gemm_qkv_kernel(
    const float* __restrict__ qin, const float* __restrict__ kin,
    const float* __restrict__ vin, const unsigned short* __restrict__ Wbase,
    const float* __restrict__ bq, const float* __restrict__ bk,
    const float* __restrict__ bv, unsigned short* __restrict__ QKout,
    unsigned short* __restrict__ VTout) {
  __shared__ __attribute__((aligned(16))) unsigned short sA[128 * 32];
  __shared__ __attribute__((aligned(16))) unsigned short sB[128 * 32];
  const int gid = blockIdx.x >> 8, rb = blockIdx.x & 255;
  const int c = rb & 7, j = rb >> 3;  // c = XCD (blockIdx round-robin, 256%8==0)
  const size_t SZA = (size_t)MROWS * D_MODEL;
  const size_t SZW = (size_t)D_MODEL * D_MODEL;
  if (gid < 2) {
    // act[MROWS,K] fp32 @ A; W[N,K] bf16 @ B. bm grouped per XCD.
    const int bm = c * 4 + (j >> 3), bn = j & 7;
    const float* act = gid == 0 ? qin : kin;
    const float* bias = gid == 0 ? bq : bk;
    const float scale = gid == 0 ? QSCALE : 1.0f;
    gemm_body128<1, 0, 0>(act, Wbase + (size_t)gid * SZW, bias, scale,
                          QKout + (size_t)gid * SZA, bm, bn, MROWS, D_MODEL,
                          D_MODEL, sA, sB);
  } else {
    // V^T: W_v[1024,K] bf16 @ A; v-act[MROWS,K] fp32 @ B. bn grouped per XCD.
    const int bm = j & 7, bn = c * 4 + (j >> 3);
    gemm_body128<0, 1, 1>(Wbase + 2 * SZW, vin, bv, 1.0f, VTout, bm, bn,
                          D_MODEL, MROWS, D_MODEL, sA, sB);
  }
}

__global__ __launch_bounds__(256, 4) void gemm_out_kernel(
    const unsigned short* __restrict__ A, const unsigned short* __restrict__ B,
    const float* __restrict__ bias, float* __restrict__ out) {
  __shared__ __attribute__((aligned(16))) unsigned short sA[128 * 32];
  __shared__ __attribute__((aligned(16))) unsigned short sB[64 * 32];
  gemm_body64(A, B, bias, out, blockIdx.x, MROWS, D_MODEL, D_MODEL, sA, sB);
}

// ---------------- flash attention (r10-proven single-pass) ----------------
// 1-D grid 512, XCD-swizzled (K/V L2-local per (b,h)). 4 waves x 32 q-rows.
// KVB=128 double-buffered as TWO 64-key sub-buffers (half the barriers).
// s_setprio(1) around PV MFMA clusters. Scale-free softmax (no max tracking);
// l via ones-MFMA row-sum (row layout, shfl-free finalize).
__global__ __launch_bounds__(256, 2) void attn_kernel(
    const unsigned short* __restrict__ Qh, const unsigned short* __restrict__ Kh,
    const unsigned short* __restrict__ Vt, unsigned short* __restrict__ Xh) {
  __shared__ __attribute__((aligned(16))) unsigned short sK[2][2][64 * 64];
  __shared__ __attribute__((aligned(16))) unsigned short sV[2][2][64 * 64];

  const int tid = threadIdx.x, w = tid >> 6, l = tid & 63;
  const int fid = blockIdx.x;
  const int L = (fid & 7) * 64 + (fid >> 3);  // XCD-chunked bijection (512%8==0)
  const int bh = L >> 4, qx = L & 15;
  const int b = bh >> 4, h = bh & 15;
  const int q0 = qx * 128 + w * 32;
  const int g = l >> 4, c16 = l & 15;

  bf16x8 qf[2][2];
#pragma unroll
  for (int qs = 0; qs < 2; ++qs)
#pragma unroll
    for (int f = 0; f < 2; ++f)
      qf[qs][f] = *(const bf16x8*)&Qh[(size_t)(b * SEQ + q0 + qs * 16 + c16) * D_MODEL +
                                      h * DK + f * 32 + g * 8];

  const u32x4 onesu = {0x3F803F80u, 0x3F803F80u, 0x3F803F80u, 0x3F803F80u};
  const bf16x8 onesf = __builtin_bit_cast(bf16x8, onesu);

  f32x4 acc[2][4], accl[2];
#pragma unroll
  for (int qs = 0; qs < 2; ++qs) {
#pragma unroll
    for (int dt = 0; dt < 4; ++dt) acc[qs][dt] = f4zero();
    accl[qs] = f4zero();
  }

  const int srow = l >> 3, sch = (l & 7) ^ (srow & 7);  // 8 rows/gload (128B rows)

  auto STAGE = [&](int pbuf, int kv0) {
#pragma unroll
    for (int half = 0; half < 2; ++half)
#pragma unroll
      for (int hh = 0; hh < 2; ++hh) {
        const int r0 = w * 16 + hh * 8;
        const int kvh = kv0 + half * 64;
        gload_lds16(
            Kh + (size_t)(b * SEQ + kvh + r0 + srow) * D_MODEL + h * DK + sch * 8,
            &sK[pbuf][half][r0 * 64]);
        gload_lds16(
            Vt + (size_t)(h * DK + r0 + srow) * MROWS + b * SEQ + kvh + sch * 8,
            &sV[pbuf][half][r0 * 64]);
      }
  };

  auto STEPH = [&](const unsigned short* sKp, const unsigned short* sVp) {
    f32x4 st[2][4];
#pragma unroll
    for (int kt = 0; kt < 4; ++kt) {
      bf16x8 kf[2];
#pragma unroll
      for (int f = 0; f < 2; ++f) {
        const int key = kt * 16 + c16;
        const int ch = (f * 4 + g) ^ (key & 7);
        kf[f] = *(const bf16x8*)&sKp[key * 64 + ch * 8];
      }
#pragma unroll
      for (int qs = 0; qs < 2; ++qs) {
        f32x4 s = mfma_bf16(kf[0], qf[qs][0], f4zero());
        st[qs][kt] = mfma_bf16(kf[1], qf[qs][1], s);
      }
    }

    unsigned int Qpk[2][4][2];
#pragma unroll
    for (int qs = 0; qs < 2; ++qs)
#pragma unroll
      for (int kt = 0; kt < 4; ++kt) {
        float pv[4];
#pragma unroll
        for (int i = 0; i < 4; ++i) pv[i] = exp2_hw(st[qs][kt][i]);
#pragma unroll
        for (int hh = 0; hh < 2; ++hh) {
          bf16x2 t2;
          t2.x = (__bf16)pv[hh * 2];
          t2.y = (__bf16)pv[hh * 2 + 1];
          Qpk[qs][kt][hh] = __builtin_bit_cast(unsigned int, t2);
        }
      }

#pragma unroll
    for (int ks = 0; ks < 2; ++ks) {
      bf16x8 pfrag[2];
#pragma unroll
      for (int qs = 0; qs < 2; ++qs) {
        unsigned int pw[4];
#if HAVE_PERMLANE_SWAP
#pragma unroll
        for (int hh = 0; hh < 2; ++hh) {
          u32x2 s1 = pl32(Qpk[qs][2 * ks][hh], Qpk[qs][2 * ks + 1][hh]);
          u32x2 s2 = pl16(s1.x, s1.y);
          pw[hh] = s2.x;
          pw[2 + hh] = s2.y;
        }
#else
#pragma unroll
        for (int hh = 0; hh < 2; ++hh) {
          const unsigned int a = Qpk[qs][2 * ks][hh], bb = Qpk[qs][2 * ks + 1][hh];
          const unsigned int as = __shfl_xor((int)a, 32);
          const unsigned int bs = __shfl_xor((int)bb, 32);
          const unsigned int r0 = (l >= 32) ? bs : a;
          const unsigned int r1 = (l >= 32) ? bb : as;
          const unsigned int t0 = __shfl_xor((int)r0, 16);
          const unsigned int t1 = __shfl_xor((int)r1, 16);
          pw[hh] = (g & 1) ? t1 : r0;
          pw[2 + hh] = (g & 1) ? r1 : t0;
        }
#endif
        u32x4 pv4 = {pw[0], pw[1], pw[2], pw[3]};
        pfrag[qs] = __builtin_bit_cast(bf16x8, pv4);
      }
      __builtin_amdgcn_s_setprio(1);
      accl[0] = mfma_bf16(pfrag[0], onesf, accl[0]);
      accl[1] = mfma_bf16(pfrag[1], onesf, accl[1]);
#pragma unroll
      for (int dt = 0; dt < 4; ++dt) {
        const int d = dt * 16 + c16;
        const int ch = (ks * 4 + g) ^ (d & 7);
        bf16x8 vfrag = *(const bf16x8*)&sVp[d * 64 + ch * 8];
        acc[0][dt] = mfma_bf16(pfrag[0], vfrag, acc[0][dt]);
        acc[1][dt] = mfma_bf16(pfrag[1], vfrag, acc[1][dt]);
      }
      __builtin_amdgcn_s_setprio(0);
    }
  };

  STAGE(0, 0);
  __syncthreads();

  for (int it = 0; it < NIT; it += 2) {  // NIT=16 even; literal buffer indices
    if (it + 1 < NIT) STAGE(1, (it + 1) * KVB);
    STEPH(&sK[0][0][0], &sV[0][0][0]);
    STEPH(&sK[0][1][0], &sV[0][1][0]);
    __syncthreads();
    if (it + 2 < NIT) STAGE(0, (it + 2) * KVB);
    STEPH(&sK[1][0][0], &sV[1][0][0]);
    STEPH(&sK[1][1][0], &sV[1][1][0]);
    __syncthreads();
  }

  // finalize: O = acc / l ; accl in ROW layout (no shfl)
#pragma unroll
  for (int qs = 0; qs < 2; ++qs) {
    float linv[4];
#pragma unroll
    for (int i = 0; i < 4; ++i) linv[i] = __builtin_amdgcn_rcpf(accl[qs][i]);
#pragma unroll
    for (int dt = 0; dt < 4; ++dt)
#pragma unroll
      for (int i = 0; i < 4; ++i) {
        const int row = b * SEQ + q0 + qs * 16 + g * 4 + i;
        const int col = h * DK + dt * 16 + c16;
        Xh[(size_t)row * D_MODEL + col] = f2b(acc[qs][dt][i] * linv[i]);
      }
  }
}

// ---------------- host ----------------
extern "C" void kernel_launch(void* const* d_in, const int* in_sizes, int n_in,
                              void* d_out, int out_size, void* d_ws, size_t ws_size,
                              hipStream_t stream) {
  (void)in_sizes; (void)n_in; (void)out_size; (void)ws_size;
  const float* q = (const float*)d_in[0];
  const float* k = (const float*)d_in[1];
  const float* v = (const float*)d_in[2];
  const float* w_q = (const float*)d_in[3];
  const float* b_q = (const float*)d_in[4];
  const float* w_k = (const float*)d_in[5];
  const float* b_k = (const float*)d_in[6];
  const float* w_v = (const float*)d_in[7];
  const float* b_v = (const float*)d_in[8];
  const float* w_o = (const float*)d_in[9];
  const float* b_o = (const float*)d_in[10];

  const size_t SZ_ACT = (size_t)MROWS * D_MODEL;  // elements (4M)
  const size_t SZ_W = (size_t)D_MODEL * D_MODEL;  // elements (1M)
  char* ws = (char*)d_ws;
  // byte layout:
  // [0,8MB):   Xh (attention output, bf16)
  // [24,40MB): Q,K projections (contig)
  // [40,48MB): V^T projection (1024 x 4096)
  // [48,56MB): wq,wk,wv,wo bf16 (contig)
  unsigned short* Xh = (unsigned short*)(ws);
  unsigned short* Qproj = (unsigned short*)(ws + 6 * SZ_ACT);
  unsigned short* Vt = (unsigned short*)(ws + 10 * SZ_ACT);
  unsigned short* wqb = (unsigned short*)(ws + 12 * SZ_ACT);
  unsigned short* wob = (unsigned short*)(ws + 12 * SZ_ACT + 6 * SZ_W);

  cvt_w_kernel<<<4096, 256, 0, stream>>>(w_q, w_k, w_v, w_o, wqb);

  gemm_qkv_kernel<<<3 * 256, 256, 0, stream>>>(q, k, v, wqb, b_q, b_k, b_v,
                                               Qproj, Vt);

  // Q at Qproj, K at Qproj + SZ_ACT (elements), V^T at Vt
  attn_kernel<<<512, 256, 0, stream>>>(Qproj, Qproj + SZ_ACT, Vt, Xh);

  gemm_out_kernel<<<512, 256, 0, stream>>>(Xh, wob, b_o, (float*)d_out);
}